// Round 9
// baseline (254.923 us; speedup 1.0000x reference)
//
#include <hip/hip_runtime.h>
#include <math.h>

#define NROWS 8192
#define KDIM  768            // elements per row; for i8 buffers this is also BYTES
#define BM 128
#define BN 128
#define BKB 128              // K-tile bytes per row (128 i8 = 2 MFMA k-steps of 64)
#define KTILES (KDIM / BKB)  // 6
#define NBC 4                // bc tiles swept per block
#define NBCG (NROWS / BN / NBC)  // 16 -> grid 64*16 = 1024 = 4/CU
#define GRID_GEMM ((NROWS / BM) * NBCG)

typedef int i32x4 __attribute__((ext_vector_type(4)));  // i8 MFMA A/B frag (16 B) and C/D

// monotonic float<->uint encoding so atomicMax(uint) == float max
static __device__ __forceinline__ unsigned enc_f(float f) {
    unsigned x = __float_as_uint(f);
    return (x & 0x80000000u) ? ~x : (x | 0x80000000u);
}
static __device__ __forceinline__ float dec_f(unsigned u) {
    unsigned x = (u & 0x80000000u) ? (u ^ 0x80000000u) : ~u;
    return __uint_as_float(x);
}

// one wave per row: fp32 normalize (exact), then symmetric int8 quantization
// with per-row scale amax/127. blocks 0..31 also init out; block 0 zeroes ctr.
__global__ __launch_bounds__(256) void normalize_quant_k(
        const float* __restrict__ ex, const float* __restrict__ ey,
        signed char* __restrict__ q, float* __restrict__ scales,
        unsigned* __restrict__ out, unsigned* __restrict__ ctr) {
    if (blockIdx.x == 0 && threadIdx.x == 0) *ctr = 0u;
    if (blockIdx.x < NROWS / 256)
        out[blockIdx.x * 256 + threadIdx.x] = enc_f(-INFINITY);
    const int wave = threadIdx.x >> 6, lane = threadIdx.x & 63;
    const int grow = blockIdx.x * 4 + wave;          // 0..16383
    const float* src = (grow < NROWS) ? ex : ey;
    const int row = grow & (NROWS - 1);
    const float4* xr = (const float4*)(src + (size_t)row * KDIM);  // 192 float4
    float4 v[3];
    #pragma unroll
    for (int g = 0; g < 3; ++g) v[g] = xr[lane + g * 64];
    float ss = 0.f, am = 0.f;
    #pragma unroll
    for (int g = 0; g < 3; ++g) {
        ss += v[g].x * v[g].x + v[g].y * v[g].y + v[g].z * v[g].z + v[g].w * v[g].w;
        am = fmaxf(am, fmaxf(fmaxf(fabsf(v[g].x), fabsf(v[g].y)),
                             fmaxf(fabsf(v[g].z), fabsf(v[g].w))));
    }
    #pragma unroll
    for (int off = 32; off > 0; off >>= 1) {
        ss += __shfl_xor(ss, off);
        am = fmaxf(am, __shfl_xor(am, off));
    }
    const float scale = 1.0f / fmaxf(sqrtf(ss), 1e-8f);
    am = fmaxf(am * scale, 1e-12f);        // amax of the NORMALIZED row
    if (lane == 0) scales[grow] = am * (1.0f / 127.0f);
    const float si = scale * (127.0f / am);            // raw -> int8 code
    int* dr = (int*)(q + (size_t)grow * KDIM);         // 192 packed ints / row
    #pragma unroll
    for (int g = 0; g < 3; ++g) {
        int qx = min(127, max(-127, __float2int_rn(v[g].x * si)));
        int qy = min(127, max(-127, __float2int_rn(v[g].y * si)));
        int qz = min(127, max(-127, __float2int_rn(v[g].z * si)));
        int qw = min(127, max(-127, __float2int_rn(v[g].w * si)));
        dr[lane + g * 64] = (qx & 0xff) | ((qy & 0xff) << 8) |
                            ((qz & 0xff) << 16) | ((qw & 0xff) << 24);
    }
}

// A = qx i8 [8192][768B], B = qy i8 [8192][768B]; sims = (A.B^T)*sa[m]*sb[n].
// R8-proven core (0 conflicts, no spill). Last-finishing block decodes out[]
// in place (threadfence + counter), eliminating the decode dispatch.
__global__ __launch_bounds__(256, 4) void gemm_rowmax_i8_k(
        const signed char* __restrict__ A, const signed char* __restrict__ B,
        const float* __restrict__ sa, const float* __restrict__ sb,
        unsigned* __restrict__ out, unsigned* __restrict__ ctr) {
    __shared__ signed char As[BM * BKB];   // 16 KB
    __shared__ signed char Bs[BN * BKB];   // 16 KB
    __shared__ unsigned lastFlag;

    const int tid  = threadIdx.x;
    const int wave = tid >> 6, lane = tid & 63;
    const int br  = blockIdx.x >> 4;       // 0..63
    const int bcg = blockIdx.x & 15;       // 0..15

    // staging: wave issue = 8 rows x 128 B; slot s of row r holds chunk s^(r&7)
    const int srow   = lane >> 3;
    const int gchunk = (lane & 7) ^ srow;
    const int scol   = gchunk * 16;        // bytes
    const signed char* aStage = A + (size_t)(br * BM + wave * 8 + srow) * KDIM + scol;
    signed char* lA = As + wave * 1024;    // + i*4096
    signed char* lB = Bs + wave * 1024;

    // compute geometry: wave 64x64, 4x4 tiles of 16x16x64
    const int wm = (wave >> 1) * 64, wn = (wave & 1) * 64;
    const int quad = lane >> 4, mrow = lane & 15;
    const int c0 = quad ^ (mrow & 7);      // swizzled chunk slot; ks=1: ^4
    const signed char* aBase = As + (wm + mrow) * BKB;
    const signed char* bBase = Bs + (wn + mrow) * BKB;
    const int row0 = br * BM + wm + quad * 4;

    #pragma unroll 1
    for (int bi = 0; bi < NBC; ++bi) {
        const int bc = bcg * NBC + bi;
        const signed char* bStage =
            B + (size_t)(bc * BN + wave * 8 + srow) * KDIM + scol;

        i32x4 acc[4][4] = {};

        #pragma unroll 1
        for (int kt = 0; kt < KTILES; ++kt) {
            __syncthreads();   // previous tile's LDS reads done
            #pragma unroll
            for (int i = 0; i < 4; ++i) {
                __builtin_amdgcn_global_load_lds(
                    (const __attribute__((address_space(1))) void*)(aStage + kt * BKB + i * 24576),
                    (__attribute__((address_space(3))) void*)(lA + i * 4096), 16, 0, 0);
                __builtin_amdgcn_global_load_lds(
                    (const __attribute__((address_space(1))) void*)(bStage + kt * BKB + i * 24576),
                    (__attribute__((address_space(3))) void*)(lB + i * 4096), 16, 0, 0);
            }
            __syncthreads();   // staging complete

            #pragma unroll 1
            for (int ks = 0; ks < 2; ++ks) {
                const int ck = c0 ^ (ks << 2);
                i32x4 af[4], bfr[4];
                #pragma unroll
                for (int mi = 0; mi < 4; ++mi)
                    af[mi] = *(const i32x4*)(aBase + mi * 16 * BKB + ck * 16);
                #pragma unroll
                for (int ni = 0; ni < 4; ++ni)
                    bfr[ni] = *(const i32x4*)(bBase + ni * 16 * BKB + ck * 16);
                #pragma unroll
                for (int mi = 0; mi < 4; ++mi)
                    #pragma unroll
                    for (int ni = 0; ni < 4; ++ni)
                        acc[mi][ni] = __builtin_amdgcn_mfma_i32_16x16x64_i8(
                            af[mi], bfr[ni], acc[mi][ni], 0, 0, 0);
            }
        }

        // epilogue: fold sb[col] per ni, in-lane ni max, shfl-max over 16 cols,
        // then *sa[row]. C/D layout: col = lane&15, row = quad*4 + reg.
        float sbv[4];
        #pragma unroll
        for (int ni = 0; ni < 4; ++ni)
            sbv[ni] = sb[bc * BN + wn + ni * 16 + mrow];
        #pragma unroll
        for (int mi = 0; mi < 4; ++mi) {
            #pragma unroll
            for (int r = 0; r < 4; ++r) {
                float v = fmaxf(fmaxf((float)acc[mi][0][r] * sbv[0],
                                      (float)acc[mi][1][r] * sbv[1]),
                                fmaxf((float)acc[mi][2][r] * sbv[2],
                                      (float)acc[mi][3][r] * sbv[3]));
                v = fmaxf(v, __shfl_xor(v, 1));
                v = fmaxf(v, __shfl_xor(v, 2));
                v = fmaxf(v, __shfl_xor(v, 4));
                v = fmaxf(v, __shfl_xor(v, 8));
                if (mrow == 0) {
                    const int row = row0 + mi * 16 + r;
                    atomicMax(&out[row], enc_f(v * sa[row]));
                }
            }
        }
    }

    // ---- last-block decode (replaces the decode dispatch)
    __threadfence();           // make this block's atomicMax results visible
    __syncthreads();
    if (tid == 0)
        lastFlag = (atomicAdd(ctr, 1u) == GRID_GEMM - 1) ? 1u : 0u;
    __syncthreads();
    if (lastFlag) {
        #pragma unroll 1
        for (int i = tid; i < NROWS; i += 256) {
            unsigned u = __hip_atomic_load(&out[i], __ATOMIC_ACQUIRE,
                                           __HIP_MEMORY_SCOPE_AGENT);
            ((float*)out)[i] = dec_f(u);
        }
    }
}

extern "C" void kernel_launch(void* const* d_in, const int* in_sizes, int n_in,
                              void* d_out, int out_size, void* d_ws, size_t ws_size,
                              hipStream_t stream) {
    (void)in_sizes; (void)n_in; (void)out_size; (void)ws_size;
    const float* ex = (const float*)d_in[0];
    const float* ey = (const float*)d_in[1];
    // ws: qx[8192*768B] ++ qy[8192*768B] ++ scales[16384 f32] ++ ctr[1 u32]
    signed char* q = (signed char*)d_ws;
    float* scales  = (float*)(q + 2 * (size_t)NROWS * KDIM);
    unsigned* ctr  = (unsigned*)(scales + 2 * NROWS);
    unsigned* outu = (unsigned*)d_out;

    normalize_quant_k<<<(2 * NROWS) / 4, 256, 0, stream>>>(ex, ey, q, scales, outu, ctr);
    gemm_rowmax_i8_k<<<GRID_GEMM, 256, 0, stream>>>(
        q, q + (size_t)NROWS * KDIM, scales, scales + NROWS, outu, ctr);
}

// Round 11
// 171.223 us; speedup vs baseline: 1.4888x; 1.4888x over previous
//
#include <hip/hip_runtime.h>
#include <math.h>

#define NROWS 8192
#define KDIM  768            // bytes per row (i8)
#define BM 128
#define BN 128
#define NCH 12               // 64-byte k-chunks per row
#define GBYTES 12288         // bytes per 16-row group (12 chunks x 1KB)
#define NBC 4                // bc tiles swept per block
#define NBCG (NROWS / BN / NBC)  // 16 -> grid 64*16 = 1024 = 4/CU

typedef int i32x4 __attribute__((ext_vector_type(4)));  // i8 MFMA A/B frag (16 B) and C/D

// monotonic float<->uint encoding so atomicMax(uint) == float max
static __device__ __forceinline__ unsigned enc_f(float f) {
    unsigned x = __float_as_uint(f);
    return (x & 0x80000000u) ? ~x : (x | 0x80000000u);
}
static __device__ __forceinline__ float dec_f(unsigned u) {
    unsigned x = (u & 0x80000000u) ? (u ^ 0x80000000u) : ~u;
    return __uint_as_float(x);
}

// Tiled quantized layout: for row-group g (16 rows) and k-chunk c (64 bytes),
// a 1KB block at (g*12 + c)*1024; byte l*16+j holds row g*16+(l&15),
// k = c*64 + (l>>4)*16 + j  == exactly lane l's mfma_i32_16x16x64_i8 fragment.
//
// One block = one 16-row group. 4 waves; wave w rows 4w..4w+3 (lane>>4 picks row,
// lane&15 picks float4 column). fp32 normalize, per-row amax/127 int8 quant.
// Stores: lane writes 12 ints; per rep the wave covers 4 dense 64B segments.
__global__ __launch_bounds__(256) void normalize_quant_k(
        const float* __restrict__ ex, const float* __restrict__ ey,
        signed char* __restrict__ qt, float* __restrict__ scales,
        unsigned* __restrict__ out) {
    const int b = blockIdx.x;                 // 0..1023 = row group over [ex;ey]
    if (b < NROWS / 256)
        out[b * 256 + threadIdx.x] = enc_f(-INFINITY);
    const int wave = threadIdx.x >> 6, lane = threadIdx.x & 63;
    const int r_local = wave * 4 + (lane >> 4);     // 0..15 row within group
    const int l16 = lane & 15;
    const int grow = b * 16 + r_local;              // 0..16383 concatenated row
    const float* src = (b < 512) ? ex : ey;
    const int Rl = ((b & 511) * 16 + r_local);      // row within source
    const float4* xr = (const float4*)(src + (size_t)Rl * KDIM);

    float4 v[NCH];
    #pragma unroll
    for (int rep = 0; rep < NCH; ++rep) v[rep] = xr[l16 + 16 * rep];

    float ss = 0.f, am = 0.f;
    #pragma unroll
    for (int rep = 0; rep < NCH; ++rep) {
        ss += v[rep].x * v[rep].x + v[rep].y * v[rep].y +
              v[rep].z * v[rep].z + v[rep].w * v[rep].w;
        am = fmaxf(am, fmaxf(fmaxf(fabsf(v[rep].x), fabsf(v[rep].y)),
                             fmaxf(fabsf(v[rep].z), fabsf(v[rep].w))));
    }
    // reduce within each 16-lane group (xor masks 1,2,4,8 stay in-group)
    #pragma unroll
    for (int off = 1; off < 16; off <<= 1) {
        ss += __shfl_xor(ss, off);
        am = fmaxf(am, __shfl_xor(am, off));
    }
    const float scale = 1.0f / fmaxf(sqrtf(ss), 1e-8f);
    am = fmaxf(am * scale, 1e-12f);                 // amax of normalized row
    if (l16 == 0) scales[grow] = am * (1.0f / 127.0f);
    const float si = scale * (127.0f / am);         // raw -> int8 code

    // tile store: lane's rep covers bytes k=64*rep + l16*4 .. +3 of its row
    signed char* gbase = qt + (size_t)b * GBYTES
                       + (l16 >> 2) * 256 + r_local * 16 + (l16 & 3) * 4;
    #pragma unroll
    for (int rep = 0; rep < NCH; ++rep) {
        int qx = min(127, max(-127, __float2int_rn(v[rep].x * si)));
        int qy = min(127, max(-127, __float2int_rn(v[rep].y * si)));
        int qz = min(127, max(-127, __float2int_rn(v[rep].z * si)));
        int qw = min(127, max(-127, __float2int_rn(v[rep].w * si)));
        *(int*)(gbase + rep * 1024) =
            (qx & 0xff) | ((qy & 0xff) << 8) | ((qz & 0xff) << 16) | ((qw & 0xff) << 24);
    }
}

// Barrier-free GEMM: fragments loaded straight from the tiled global layout
// (wave-coalesced 1KB per load, L2/L3 resident). No LDS, no __syncthreads —
// waves pipeline independently (the structural fix for the barrier-drain tax).
__global__ __launch_bounds__(256, 4) void gemm_rowmax_i8_k(
        const signed char* __restrict__ A, const signed char* __restrict__ B,
        const float* __restrict__ sa, const float* __restrict__ sb,
        unsigned* __restrict__ out) {
    const int tid  = threadIdx.x;
    const int wave = tid >> 6, lane = tid & 63;
    const int br  = blockIdx.x >> 4;       // 0..63
    const int bcg = blockIdx.x & 15;       // 0..15

    const int wgA = (wave >> 1) * 4;       // A row-group offset within 8-group band
    const int wgB = (wave & 1) * 4;        // B row-group offset
    const size_t laneoff = (size_t)lane * 16;

    const signed char* aT = A + (size_t)(br * 8 + wgA) * GBYTES + laneoff;
    const int quad = lane >> 4, mrow = lane & 15;
    const int row0 = br * BM + wgA * 16 + quad * 4;

    #pragma unroll 1
    for (int bi = 0; bi < NBC; ++bi) {
        const int bc = bcg * NBC + bi;
        const signed char* bT = B + (size_t)(bc * 8 + wgB) * GBYTES + laneoff;

        i32x4 acc[4][4] = {};

        #pragma unroll 1
        for (int c = 0; c < NCH; ++c) {
            i32x4 af[4], bfr[4];
            #pragma unroll
            for (int mi = 0; mi < 4; ++mi)
                af[mi] = *(const i32x4*)(aT + (size_t)mi * GBYTES + c * 1024);
            #pragma unroll
            for (int ni = 0; ni < 4; ++ni)
                bfr[ni] = *(const i32x4*)(bT + (size_t)ni * GBYTES + c * 1024);
            #pragma unroll
            for (int mi = 0; mi < 4; ++mi)
                #pragma unroll
                for (int ni = 0; ni < 4; ++ni)
                    acc[mi][ni] = __builtin_amdgcn_mfma_i32_16x16x64_i8(
                        af[mi], bfr[ni], acc[mi][ni], 0, 0, 0);
        }

        // epilogue: fold sb[col] per ni, in-lane ni max, shfl-max over 16 cols,
        // then *sa[row]. C/D layout: col = lane&15, row = quad*4 + reg.
        float sbv[4];
        #pragma unroll
        for (int ni = 0; ni < 4; ++ni)
            sbv[ni] = sb[bc * BN + wgB * 16 + ni * 16 + mrow];
        #pragma unroll
        for (int mi = 0; mi < 4; ++mi) {
            #pragma unroll
            for (int r = 0; r < 4; ++r) {
                float v = fmaxf(fmaxf((float)acc[mi][0][r] * sbv[0],
                                      (float)acc[mi][1][r] * sbv[1]),
                                fmaxf((float)acc[mi][2][r] * sbv[2],
                                      (float)acc[mi][3][r] * sbv[3]));
                v = fmaxf(v, __shfl_xor(v, 1));
                v = fmaxf(v, __shfl_xor(v, 2));
                v = fmaxf(v, __shfl_xor(v, 4));
                v = fmaxf(v, __shfl_xor(v, 8));
                if (mrow == 0) {
                    const int row = row0 + mi * 16 + r;
                    atomicMax(&out[row], enc_f(v * sa[row]));
                }
            }
        }
    }
}

__global__ void decode_out_k(unsigned* __restrict__ u) {
    int i = blockIdx.x * 256 + threadIdx.x;
    ((float*)u)[i] = dec_f(u[i]);
}

extern "C" void kernel_launch(void* const* d_in, const int* in_sizes, int n_in,
                              void* d_out, int out_size, void* d_ws, size_t ws_size,
                              hipStream_t stream) {
    (void)in_sizes; (void)n_in; (void)out_size; (void)ws_size;
    const float* ex = (const float*)d_in[0];
    const float* ey = (const float*)d_in[1];
    // ws: qxT[512 groups * 12KB] ++ qyT[same] ++ scales[16384 f32]  (~12.65 MB)
    signed char* q = (signed char*)d_ws;
    float* scales  = (float*)(q + 2 * (size_t)512 * GBYTES);
    unsigned* outu = (unsigned*)d_out;

    normalize_quant_k<<<1024, 256, 0, stream>>>(ex, ey, q, scales, outu);
    gemm_rowmax_i8_k<<<(NROWS / BM) * NBCG, 256, 0, stream>>>(
        q, q + (size_t)512 * GBYTES, scales, scales + NROWS, outu);
    decode_out_k<<<NROWS / 256, 256, 0, stream>>>(outu);
}

// Round 12
// 169.740 us; speedup vs baseline: 1.5018x; 1.0087x over previous
//
#include <hip/hip_runtime.h>
#include <math.h>

#define NROWS 8192
#define KDIM  768            // bytes per row (i8)
#define BM 128
#define BN 128
#define NCH 12               // 64-byte k-chunks per row
#define GBYTES 12288         // bytes per 16-row group (12 chunks x 1KB)
#define NBC 4                // bc tiles swept per block
#define NBCG (NROWS / BN / NBC)  // 16 -> grid 64*16 = 1024 = 4/CU

typedef int i32x4 __attribute__((ext_vector_type(4)));  // i8 MFMA A/B frag (16 B) and C/D

// monotonic float<->uint encoding so atomicMax(uint) == float max
static __device__ __forceinline__ unsigned enc_f(float f) {
    unsigned x = __float_as_uint(f);
    return (x & 0x80000000u) ? ~x : (x | 0x80000000u);
}
static __device__ __forceinline__ float dec_f(unsigned u) {
    unsigned x = (u & 0x80000000u) ? (u ^ 0x80000000u) : ~u;
    return __uint_as_float(x);
}

// Tiled quantized layout: for row-group g (16 rows) and k-chunk c (64 bytes),
// a 1KB block at (g*12 + c)*1024; byte l*16+j holds row g*16+(l&15),
// k = c*64 + (l>>4)*16 + j  == exactly lane l's mfma_i32_16x16x64_i8 fragment.
__global__ __launch_bounds__(256) void normalize_quant_k(
        const float* __restrict__ ex, const float* __restrict__ ey,
        signed char* __restrict__ qt, float* __restrict__ scales,
        unsigned* __restrict__ out) {
    const int b = blockIdx.x;                 // 0..1023 = row group over [ex;ey]
    if (b < NROWS / 256)
        out[b * 256 + threadIdx.x] = enc_f(-INFINITY);
    const int wave = threadIdx.x >> 6, lane = threadIdx.x & 63;
    const int r_local = wave * 4 + (lane >> 4);     // 0..15 row within group
    const int l16 = lane & 15;
    const int grow = b * 16 + r_local;              // 0..16383 concatenated row
    const float* src = (b < 512) ? ex : ey;
    const int Rl = ((b & 511) * 16 + r_local);      // row within source
    const float4* xr = (const float4*)(src + (size_t)Rl * KDIM);

    float4 v[NCH];
    #pragma unroll
    for (int rep = 0; rep < NCH; ++rep) v[rep] = xr[l16 + 16 * rep];

    float ss = 0.f, am = 0.f;
    #pragma unroll
    for (int rep = 0; rep < NCH; ++rep) {
        ss += v[rep].x * v[rep].x + v[rep].y * v[rep].y +
              v[rep].z * v[rep].z + v[rep].w * v[rep].w;
        am = fmaxf(am, fmaxf(fmaxf(fabsf(v[rep].x), fabsf(v[rep].y)),
                             fmaxf(fabsf(v[rep].z), fabsf(v[rep].w))));
    }
    // reduce within each 16-lane group (xor masks 1,2,4,8 stay in-group)
    #pragma unroll
    for (int off = 1; off < 16; off <<= 1) {
        ss += __shfl_xor(ss, off);
        am = fmaxf(am, __shfl_xor(am, off));
    }
    const float scale = 1.0f / fmaxf(sqrtf(ss), 1e-8f);
    am = fmaxf(am * scale, 1e-12f);                 // amax of normalized row
    if (l16 == 0) scales[grow] = am * (1.0f / 127.0f);
    const float si = scale * (127.0f / am);         // raw -> int8 code

    // tile store: lane's rep covers bytes k=64*rep + l16*4 .. +3 of its row
    signed char* gbase = qt + (size_t)b * GBYTES
                       + (l16 >> 2) * 256 + r_local * 16 + (l16 & 3) * 4;
    #pragma unroll
    for (int rep = 0; rep < NCH; ++rep) {
        int qx = min(127, max(-127, __float2int_rn(v[rep].x * si)));
        int qy = min(127, max(-127, __float2int_rn(v[rep].y * si)));
        int qz = min(127, max(-127, __float2int_rn(v[rep].z * si)));
        int qw = min(127, max(-127, __float2int_rn(v[rep].w * si)));
        *(int*)(gbase + rep * 1024) =
            (qx & 0xff) | ((qy & 0xff) << 8) | ((qz & 0xff) << 16) | ((qw & 0xff) << 24);
    }
}

// Barrier-free GEMM from the tiled global layout. R12 change: 2D region swizzle
// (id%8 = region of 16 br x 8 bcg) so that under round-robin id->XCD each XCD's
// blocks touch only A 1.5 MB + B 3 MB ~= its 4 MB L2 (both operands resident).
// Under a chunked/unknown mapping this degrades to the R11 blend (neutral).
__global__ __launch_bounds__(256, 4) void gemm_rowmax_i8_k(
        const signed char* __restrict__ A, const signed char* __restrict__ B,
        const float* __restrict__ sa, const float* __restrict__ sb,
        unsigned* __restrict__ out) {
    const int tid  = threadIdx.x;
    const int wave = tid >> 6, lane = tid & 63;

    const int id    = blockIdx.x;
    const int reg8  = id & 7;              // region (XCD under round-robin)
    const int inner = id >> 3;             // 0..127 within region
    const int br  = (reg8 & 3) * 16 + (inner & 15);   // 0..63
    const int bcg = (reg8 >> 2) * 8 + (inner >> 4);   // 0..15

    const int wgA = (wave >> 1) * 4;       // A row-group offset within 8-group band
    const int wgB = (wave & 1) * 4;        // B row-group offset
    const size_t laneoff = (size_t)lane * 16;

    const signed char* aT = A + (size_t)(br * 8 + wgA) * GBYTES + laneoff;
    const int quad = lane >> 4, mrow = lane & 15;
    const int row0 = br * BM + wgA * 16 + quad * 4;

    #pragma unroll 1
    for (int bi = 0; bi < NBC; ++bi) {
        const int bc = bcg * NBC + bi;
        const signed char* bT = B + (size_t)(bc * 8 + wgB) * GBYTES + laneoff;

        i32x4 acc[4][4] = {};

        #pragma unroll 1
        for (int c = 0; c < NCH; ++c) {
            i32x4 af[4], bfr[4];
            #pragma unroll
            for (int mi = 0; mi < 4; ++mi)
                af[mi] = *(const i32x4*)(aT + (size_t)mi * GBYTES + c * 1024);
            #pragma unroll
            for (int ni = 0; ni < 4; ++ni)
                bfr[ni] = *(const i32x4*)(bT + (size_t)ni * GBYTES + c * 1024);
            #pragma unroll
            for (int mi = 0; mi < 4; ++mi)
                #pragma unroll
                for (int ni = 0; ni < 4; ++ni)
                    acc[mi][ni] = __builtin_amdgcn_mfma_i32_16x16x64_i8(
                        af[mi], bfr[ni], acc[mi][ni], 0, 0, 0);
        }

        // epilogue: fold sb[col] per ni, in-lane ni max, shfl-max over 16 cols,
        // then *sa[row]. C/D layout: col = lane&15, row = quad*4 + reg.
        float sbv[4];
        #pragma unroll
        for (int ni = 0; ni < 4; ++ni)
            sbv[ni] = sb[bc * BN + wgB * 16 + ni * 16 + mrow];
        #pragma unroll
        for (int mi = 0; mi < 4; ++mi) {
            #pragma unroll
            for (int r = 0; r < 4; ++r) {
                float v = fmaxf(fmaxf((float)acc[mi][0][r] * sbv[0],
                                      (float)acc[mi][1][r] * sbv[1]),
                                fmaxf((float)acc[mi][2][r] * sbv[2],
                                      (float)acc[mi][3][r] * sbv[3]));
                v = fmaxf(v, __shfl_xor(v, 1));
                v = fmaxf(v, __shfl_xor(v, 2));
                v = fmaxf(v, __shfl_xor(v, 4));
                v = fmaxf(v, __shfl_xor(v, 8));
                if (mrow == 0) {
                    const int row = row0 + mi * 16 + r;
                    atomicMax(&out[row], enc_f(v * sa[row]));
                }
            }
        }
    }
}

__global__ void decode_out_k(unsigned* __restrict__ u) {
    int i = blockIdx.x * 256 + threadIdx.x;
    ((float*)u)[i] = dec_f(u[i]);
}

extern "C" void kernel_launch(void* const* d_in, const int* in_sizes, int n_in,
                              void* d_out, int out_size, void* d_ws, size_t ws_size,
                              hipStream_t stream) {
    (void)in_sizes; (void)n_in; (void)out_size; (void)ws_size;
    const float* ex = (const float*)d_in[0];
    const float* ey = (const float*)d_in[1];
    // ws: qxT[512 groups * 12KB] ++ qyT[same] ++ scales[16384 f32]  (~12.65 MB)
    signed char* q = (signed char*)d_ws;
    float* scales  = (float*)(q + 2 * (size_t)512 * GBYTES);
    unsigned* outu = (unsigned*)d_out;

    normalize_quant_k<<<1024, 256, 0, stream>>>(ex, ey, q, scales, outu);
    gemm_rowmax_i8_k<<<(NROWS / BM) * NBCG, 256, 0, stream>>>(
        q, q + (size_t)512 * GBYTES, scales, scales + NROWS, outu);
    decode_out_k<<<NROWS / 256, 256, 0, stream>>>(outu);
}

// Round 13
// 163.179 us; speedup vs baseline: 1.5622x; 1.0402x over previous
//
#include <hip/hip_runtime.h>
#include <math.h>

#define NROWS 8192
#define KDIM  768            // elements per row; for i8 buffers this is also BYTES
#define BM 128
#define BN 128
#define BKB 128              // K-tile bytes per row (128 i8 = 2 MFMA k-steps of 64)
#define KTILES (KDIM / BKB)  // 6
#define NBC 4                // bc tiles swept per block
#define NBCG (NROWS / BN / NBC)  // 16 -> grid 64*16 = 1024 = 4/CU

typedef int i32x4 __attribute__((ext_vector_type(4)));  // i8 MFMA A/B frag (16 B) and C/D

// monotonic float<->uint encoding so atomicMax(uint) == float max
static __device__ __forceinline__ unsigned enc_f(float f) {
    unsigned x = __float_as_uint(f);
    return (x & 0x80000000u) ? ~x : (x | 0x80000000u);
}
static __device__ __forceinline__ float dec_f(unsigned u) {
    unsigned x = (u & 0x80000000u) ? (u ^ 0x80000000u) : ~u;
    return __uint_as_float(x);
}

// one wave per row: fp32 normalize (exact), then symmetric int8 quantization
// with per-row scale amax/127. blocks 0..31 also init the out buffer. (R8-proven)
__global__ __launch_bounds__(256) void normalize_quant_k(
        const float* __restrict__ ex, const float* __restrict__ ey,
        signed char* __restrict__ q, float* __restrict__ scales,
        unsigned* __restrict__ out) {
    if (blockIdx.x < NROWS / 256)
        out[blockIdx.x * 256 + threadIdx.x] = enc_f(-INFINITY);
    const int wave = threadIdx.x >> 6, lane = threadIdx.x & 63;
    const int grow = blockIdx.x * 4 + wave;          // 0..16383
    const float* src = (grow < NROWS) ? ex : ey;
    const int row = grow & (NROWS - 1);
    const float4* xr = (const float4*)(src + (size_t)row * KDIM);  // 192 float4
    float4 v[3];
    #pragma unroll
    for (int g = 0; g < 3; ++g) v[g] = xr[lane + g * 64];
    float ss = 0.f, am = 0.f;
    #pragma unroll
    for (int g = 0; g < 3; ++g) {
        ss += v[g].x * v[g].x + v[g].y * v[g].y + v[g].z * v[g].z + v[g].w * v[g].w;
        am = fmaxf(am, fmaxf(fmaxf(fabsf(v[g].x), fabsf(v[g].y)),
                             fmaxf(fabsf(v[g].z), fabsf(v[g].w))));
    }
    #pragma unroll
    for (int off = 32; off > 0; off >>= 1) {
        ss += __shfl_xor(ss, off);
        am = fmaxf(am, __shfl_xor(am, off));
    }
    const float scale = 1.0f / fmaxf(sqrtf(ss), 1e-8f);
    am = fmaxf(am * scale, 1e-12f);        // amax of the NORMALIZED row
    if (lane == 0) scales[grow] = am * (1.0f / 127.0f);
    const float si = scale * (127.0f / am);            // raw -> int8 code
    int* dr = (int*)(q + (size_t)grow * KDIM);         // 192 packed ints / row
    #pragma unroll
    for (int g = 0; g < 3; ++g) {
        int qx = min(127, max(-127, __float2int_rn(v[g].x * si)));
        int qy = min(127, max(-127, __float2int_rn(v[g].y * si)));
        int qz = min(127, max(-127, __float2int_rn(v[g].z * si)));
        int qw = min(127, max(-127, __float2int_rn(v[g].w * si)));
        dr[lane + g * 64] = (qx & 0xff) | ((qy & 0xff) << 8) |
                            ((qz & 0xff) << 16) | ((qw & 0xff) << 24);
    }
}

// A = qx i8 [8192][768B], B = qy i8 [8192][768B]; sims = (A.B^T)*sa[m]*sb[n].
// R8-proven LDS core (0 conflicts, no spill, 81.5 us) + R12-proven region
// swizzle: id%8 selects a 16br x 8bcg region so each XCD's blocks touch
// A 1.5MB + B 3MB ~= its 4MB L2 -> staging loads become L2-hits, shortening
// the per-K-tile vmcnt(0) barrier drains (the structure's residual cost).
__global__ __launch_bounds__(256, 4) void gemm_rowmax_i8_k(
        const signed char* __restrict__ A, const signed char* __restrict__ B,
        const float* __restrict__ sa, const float* __restrict__ sb,
        unsigned* __restrict__ out) {
    __shared__ signed char As[BM * BKB];   // 16 KB
    __shared__ signed char Bs[BN * BKB];   // 16 KB

    const int tid  = threadIdx.x;
    const int wave = tid >> 6, lane = tid & 63;

    // region swizzle (R12): region = 16 br x 8 bcg, id%8 picks region
    const int id    = blockIdx.x;
    const int reg8  = id & 7;
    const int inner = id >> 3;                        // 0..127 within region
    const int br  = (reg8 & 3) * 16 + (inner & 15);   // 0..63
    const int bcg = (reg8 >> 2) * 8 + (inner >> 4);   // 0..15

    // staging: wave issue = 8 rows x 128 B; slot s of row r holds chunk s^(r&7)
    const int srow   = lane >> 3;
    const int gchunk = (lane & 7) ^ srow;
    const int scol   = gchunk * 16;        // bytes
    const signed char* aStage = A + (size_t)(br * BM + wave * 8 + srow) * KDIM + scol;
    signed char* lA = As + wave * 1024;    // + i*4096
    signed char* lB = Bs + wave * 1024;

    // compute geometry: wave 64x64, 4x4 tiles of 16x16x64
    const int wm = (wave >> 1) * 64, wn = (wave & 1) * 64;
    const int quad = lane >> 4, mrow = lane & 15;
    const int c0 = quad ^ (mrow & 7);      // swizzled chunk slot; ks=1: ^4
    const signed char* aBase = As + (wm + mrow) * BKB;
    const signed char* bBase = Bs + (wn + mrow) * BKB;
    const int row0 = br * BM + wm + quad * 4;

    #pragma unroll 1
    for (int bi = 0; bi < NBC; ++bi) {
        const int bc = bcg * NBC + bi;
        const signed char* bStage =
            B + (size_t)(bc * BN + wave * 8 + srow) * KDIM + scol;

        i32x4 acc[4][4] = {};

        #pragma unroll 1
        for (int kt = 0; kt < KTILES; ++kt) {
            __syncthreads();   // previous tile's LDS reads done
            #pragma unroll
            for (int i = 0; i < 4; ++i) {
                __builtin_amdgcn_global_load_lds(
                    (const __attribute__((address_space(1))) void*)(aStage + kt * BKB + i * 24576),
                    (__attribute__((address_space(3))) void*)(lA + i * 4096), 16, 0, 0);
                __builtin_amdgcn_global_load_lds(
                    (const __attribute__((address_space(1))) void*)(bStage + kt * BKB + i * 24576),
                    (__attribute__((address_space(3))) void*)(lB + i * 4096), 16, 0, 0);
            }
            __syncthreads();   // staging complete

            #pragma unroll 1
            for (int ks = 0; ks < 2; ++ks) {
                const int ck = c0 ^ (ks << 2);
                i32x4 af[4], bfr[4];
                #pragma unroll
                for (int mi = 0; mi < 4; ++mi)
                    af[mi] = *(const i32x4*)(aBase + mi * 16 * BKB + ck * 16);
                #pragma unroll
                for (int ni = 0; ni < 4; ++ni)
                    bfr[ni] = *(const i32x4*)(bBase + ni * 16 * BKB + ck * 16);
                #pragma unroll
                for (int mi = 0; mi < 4; ++mi)
                    #pragma unroll
                    for (int ni = 0; ni < 4; ++ni)
                        acc[mi][ni] = __builtin_amdgcn_mfma_i32_16x16x64_i8(
                            af[mi], bfr[ni], acc[mi][ni], 0, 0, 0);
            }
        }

        // epilogue: fold sb[col] per ni, in-lane ni max, shfl-max over 16 cols,
        // then *sa[row]. C/D layout: col = lane&15, row = quad*4 + reg.
        float sbv[4];
        #pragma unroll
        for (int ni = 0; ni < 4; ++ni)
            sbv[ni] = sb[bc * BN + wn + ni * 16 + mrow];
        #pragma unroll
        for (int mi = 0; mi < 4; ++mi) {
            #pragma unroll
            for (int r = 0; r < 4; ++r) {
                float v = fmaxf(fmaxf((float)acc[mi][0][r] * sbv[0],
                                      (float)acc[mi][1][r] * sbv[1]),
                                fmaxf((float)acc[mi][2][r] * sbv[2],
                                      (float)acc[mi][3][r] * sbv[3]));
                v = fmaxf(v, __shfl_xor(v, 1));
                v = fmaxf(v, __shfl_xor(v, 2));
                v = fmaxf(v, __shfl_xor(v, 4));
                v = fmaxf(v, __shfl_xor(v, 8));
                if (mrow == 0) {
                    const int row = row0 + mi * 16 + r;
                    atomicMax(&out[row], enc_f(v * sa[row]));
                }
            }
        }
    }
}

__global__ void decode_out_k(unsigned* __restrict__ u) {
    int i = blockIdx.x * 256 + threadIdx.x;
    ((float*)u)[i] = dec_f(u[i]);
}

extern "C" void kernel_launch(void* const* d_in, const int* in_sizes, int n_in,
                              void* d_out, int out_size, void* d_ws, size_t ws_size,
                              hipStream_t stream) {
    (void)in_sizes; (void)n_in; (void)out_size; (void)ws_size;
    const float* ex = (const float*)d_in[0];
    const float* ey = (const float*)d_in[1];
    // ws: qx[8192*768B] ++ qy[8192*768B] ++ scales[16384 f32]  (~12.6 MB)
    signed char* q = (signed char*)d_ws;
    float* scales  = (float*)(q + 2 * (size_t)NROWS * KDIM);
    unsigned* outu = (unsigned*)d_out;

    normalize_quant_k<<<(2 * NROWS) / 4, 256, 0, stream>>>(ex, ey, q, scales, outu);
    gemm_rowmax_i8_k<<<(NROWS / BM) * NBCG, 256, 0, stream>>>(
        q, q + (size_t)NROWS * KDIM, scales, scales + NROWS, outu);
    decode_out_k<<<NROWS / 256, 256, 0, stream>>>(outu);
}